// Round 24
// baseline (30.015 us; speedup 1.0000x reference)
//
#include <hip/hip_runtime.h>

#define DIM   256
#define CLS   512
#define NGF   32640          // packed strict-upper-triangle floats per class
#define NQ    8160           // NGF/4 float4 quads
#define NITER 4
#define PSH   72             // y part-slice stride in h16

typedef _Float16 h16;
typedef __attribute__((ext_vector_type(2))) _Float16 h16x2;

__device__ __forceinline__ float dot2f(unsigned a, unsigned b, float c) {
    return __builtin_amdgcn_fdot2(__builtin_bit_cast(h16x2, a),
                                  __builtin_bit_cast(h16x2, b), c, false);
}

__device__ __forceinline__ unsigned pkrtz(float lo, float hi) {
    return __builtin_bit_cast(unsigned, __builtin_amdgcn_cvt_pkrtz(lo, hi));
}

__device__ __forceinline__ uint2 cvt2(float4 v) {
    uint2 d;
    d.x = pkrtz(0.5f * v.x, 0.5f * v.y);
    d.y = pkrtz(0.5f * v.z, 0.5f * v.w);
    return d;
}

// barrier draining LDS only
__device__ __forceinline__ void bar_lds() {
    asm volatile("s_waitcnt lgkmcnt(0)\n\ts_barrier" ::: "memory");
}

// y[g] at part(g)*PSH + slot(g): part=(g>>4)&3, slot=((g>>6)<<4)|(g&15)
__device__ __forceinline__ int yaddr(int g) {
    return ((g >> 4) & 3) * PSH + (((g >> 6) << 4) | (g & 15));
}

// gather S[r][.] owned columns {64a+16p+t} -> sreg, 3-path (from R19)
#define GATHER(UH, UD)                                                     \
    do {                                                                   \
        _Pragma("unroll")                                                  \
        for (int a = 0; a < 4; ++a) {                                      \
            const int g0 = 64 * a + 16 * p;                                \
            if (g0 > r) {                                                  \
                int au0 = offr + g0;                                       \
                unsigned d[9];                                             \
                _Pragma("unroll")                                          \
                for (int i = 0; i < 9; ++i) d[i] = (UD)[(au0 >> 1) + i];   \
                const bool odd = (au0 & 1);                                \
                _Pragma("unroll")                                          \
                for (int i = 0; i < 8; ++i) {                              \
                    unsigned ev = d[i];                                    \
                    unsigned od = __builtin_amdgcn_alignbit(d[i+1], d[i], 16); \
                    sreg[8 * a + i] = odd ? od : ev;                       \
                }                                                          \
            } else if (g0 + 15 < r) {                                      \
                int g  = g0;                                               \
                int al = ((g0 * (511 - g0)) >> 1) + r - g0 - 1;            \
                unsigned wacc = 0;                                         \
                _Pragma("unroll")                                          \
                for (int t = 0; t < 16; ++t) {                             \
                    unsigned h = (UH)[al] ^ 0x8000u;                       \
                    if (t & 1) { wacc |= h << 16; sreg[8*a+(t>>1)] = wacc; } \
                    else       { wacc  = h; }                              \
                    al += 254 - g;                                         \
                    ++g;                                                   \
                }                                                          \
            } else {                                                       \
                int g  = g0;                                               \
                int au = offr + g0;                                        \
                int al = ((g0 * (511 - g0)) >> 1) + r - g0 - 1;            \
                unsigned wacc = 0;                                         \
                _Pragma("unroll")                                          \
                for (int t = 0; t < 16; ++t) {                             \
                    int idx = (g < r) ? al : au;                           \
                    idx = idx < 0 ? 0 : idx;                               \
                    unsigned h = (UH)[idx];                                \
                    h = (g < r) ? (h ^ 0x8000u) : h;                       \
                    h = (g == r) ? 0u : h;                                 \
                    if (t & 1) { wacc |= h << 16; sreg[8*a+(t>>1)] = wacc; } \
                    else       { wacc  = h; }                              \
                    ++au;                                                  \
                    al += 254 - g;                                         \
                    ++g;                                                   \
                }                                                          \
            }                                                              \
        }                                                                  \
    } while (0)

#define ITERATE(XR, CC)                                                    \
    do {                                                                   \
        h16* ycur = sy0;                                                   \
        h16* ynxt = sy1;                                                   \
        _Pragma("unroll")                                                  \
        for (int it = 0; it < NITER; ++it) {                               \
            const uint4* yp = (const uint4*)(ycur + p * PSH);              \
            float a0 = 0.f, a1 = 0.f, a2 = 0.f, a3 = 0.f;                  \
            _Pragma("unroll")                                              \
            for (int k = 0; k < 8; ++k) {                                  \
                uint4 yv = yp[k];                                          \
                a0 = dot2f(sreg[4*k+0], yv.x, a0);                         \
                a1 = dot2f(sreg[4*k+1], yv.y, a1);                         \
                a2 = dot2f(sreg[4*k+2], yv.z, a2);                         \
                a3 = dot2f(sreg[4*k+3], yv.w, a3);                         \
            }                                                              \
            float v = (a0 + a1) + (a2 + a3);                               \
            v += __shfl_xor(v, 1);                                         \
            v += __shfl_xor(v, 2);                                         \
            if (it < NITER - 1) {                                          \
                if (p == 0) ynxt[wr] = (h16)((XR) - v);                    \
                h16* t = ycur; ycur = ynxt; ynxt = t;                      \
                bar_lds();                                                 \
            } else {                                                       \
                if (p == 0) out[(size_t)r * CLS + (CC)] = (XR) - 2.f * v;  \
            }                                                              \
        }                                                                  \
    } while (0)

__global__ void __launch_bounds__(1024)
cayley_kernel(const float* __restrict__ x, const float* __restrict__ W,
              float* __restrict__ out) {
    extern __shared__ char smem[];
    unsigned short* U0h = (unsigned short*)smem;           // 64 KB f16(0.5*W[cA])
    unsigned*       U0d = (unsigned*)smem;
    uint2*          U0q = (uint2*)smem;
    unsigned short* U1h = (unsigned short*)(smem + 65536); // 64 KB f16(0.5*W[cB])
    unsigned*       U1d = (unsigned*)(smem + 65536);
    uint2*          U1q = (uint2*)(smem + 65536);
    h16* sy0 = (h16*)(smem + 131072);                      // 576 B
    h16* sy1 = sy0 + 4 * PSH;                              // 576 B

    const int tid  = threadIdx.x;
    const int r    = tid >> 2;       // row 0..255
    const int p    = tid & 3;        // part: owns columns {64a + 16p + t}
    const int cA   = blockIdx.x;
    const int cB   = blockIdx.x + 256;
    const int offr = (r * (511 - r)) / 2 - r - 1;
    const int wr   = yaddr(r);

    const float xrA = x[(size_t)r * CLS + cA];
    const float xrB = x[(size_t)r * CLS + cB];

    // ===== deep stage: A then B, depth-4 rotation (<=4 loads in flight) =====
    {
        const float4* WA4 = (const float4*)(W + (size_t)cA * NGF);
        const float4* WB4 = (const float4*)(W + (size_t)cB * NGF);
        float4 v0 = WA4[tid];
        float4 v1 = WA4[tid + 1024];
        float4 v2 = WA4[tid + 2048];
        float4 v3 = WA4[tid + 3072];
        U0q[tid]        = cvt2(v0);  v0 = WA4[tid + 4096];
        U0q[tid + 1024] = cvt2(v1);  v1 = WA4[tid + 5120];
        U0q[tid + 2048] = cvt2(v2);  v2 = WA4[tid + 6144];
        int qa = tid + 7168;
        U0q[tid + 3072] = cvt2(v3);  v3 = WA4[qa < NQ ? qa : 0];
        U0q[tid + 4096] = cvt2(v0);  v0 = WB4[tid];
        U0q[tid + 5120] = cvt2(v1);  v1 = WB4[tid + 1024];
        U0q[tid + 6144] = cvt2(v2);  v2 = WB4[tid + 2048];
        if (qa < NQ) U0q[qa] = cvt2(v3);
        v3 = WB4[tid + 3072];
        U1q[tid]        = cvt2(v0);  v0 = WB4[tid + 4096];
        U1q[tid + 1024] = cvt2(v1);  v1 = WB4[tid + 5120];
        U1q[tid + 2048] = cvt2(v2);  v2 = WB4[tid + 6144];
        U1q[tid + 3072] = cvt2(v3);  v3 = WB4[qa < NQ ? qa : 0];
        U1q[tid + 4096] = cvt2(v0);
        U1q[tid + 5120] = cvt2(v1);
        U1q[tid + 6144] = cvt2(v2);
        if (qa < NQ) U1q[qa] = cvt2(v3);
    }
    if (p == 0) sy0[wr] = (h16)xrA;
    __syncthreads();                        // U0, U1, y0(A) all visible

    // ===== class A =====
    unsigned sreg[32];
    GATHER(U0h, U0d);
    ITERATE(xrA, cA);

    // ===== class B (U1 untouched by iterate; only y-handoff needs a bar) =====
    if (p == 0) sy0[wr] = (h16)xrB;         // safe: A's last read was sy1
    GATHER(U1h, U1d);
    bar_lds();                              // y0(B) visible; A's sy reads done

    ITERATE(xrB, cB);
}

extern "C" void kernel_launch(void* const* d_in, const int* in_sizes, int n_in,
                              void* d_out, int out_size, void* d_ws, size_t ws_size,
                              hipStream_t stream) {
    const float* x = (const float*)d_in[0];
    const float* W = (const float*)d_in[1];
    float* out = (float*)d_out;

    const size_t smem = 131072 + 2 * 4 * PSH * 2;   // 132224 B -> 1 block/CU
    hipFuncSetAttribute((const void*)cayley_kernel,
                        hipFuncAttributeMaxDynamicSharedMemorySize, (int)smem);
    hipLaunchKernelGGL(cayley_kernel, dim3(CLS / 2), dim3(1024), smem, stream, x, W, out);
}

// Round 25
// 27.299 us; speedup vs baseline: 1.0995x; 1.0995x over previous
//
#include <hip/hip_runtime.h>

#define DIM   256
#define CLS   512
#define NGF   32640          // packed strict-upper-triangle floats per class
#define NQ    8160           // NGF/4 float4 quads
#define NITER 4
#define PSH   72             // y part-slice stride in h16

typedef _Float16 h16;
typedef __attribute__((ext_vector_type(2))) _Float16 h16x2;

__device__ __forceinline__ float dot2f(unsigned a, unsigned b, float c) {
    return __builtin_amdgcn_fdot2(__builtin_bit_cast(h16x2, a),
                                  __builtin_bit_cast(h16x2, b), c, false);
}

__device__ __forceinline__ unsigned pkrtz(float lo, float hi) {
    return __builtin_bit_cast(unsigned, __builtin_amdgcn_cvt_pkrtz(lo, hi));
}

__device__ __forceinline__ uint2 cvt2(float4 v) {
    uint2 d;
    d.x = pkrtz(0.5f * v.x, 0.5f * v.y);
    d.y = pkrtz(0.5f * v.z, 0.5f * v.w);
    return d;
}

// barrier draining LDS only
__device__ __forceinline__ void bar_lds() {
    asm volatile("s_waitcnt lgkmcnt(0)\n\ts_barrier" ::: "memory");
}

// y[g] at part(g)*PSH + slot(g): part=(g>>4)&3, slot=((g>>6)<<4)|(g&15)
__device__ __forceinline__ int yaddr(int g) {
    return ((g >> 4) & 3) * PSH + (((g >> 6) << 4) | (g & 15));
}

__global__ void __launch_bounds__(1024)
cayley_kernel(const float* __restrict__ x, const float* __restrict__ W,
              float* __restrict__ out) {
    extern __shared__ char smem[];
    unsigned short* U  = (unsigned short*)smem;        // 65536 B: f16(0.5*W) packed triu
    unsigned*       Ud = (unsigned*)smem;
    uint2*          U2 = (uint2*)smem;
    h16* sy0 = (h16*)(smem + 65536);                   // 576 B
    h16* sy1 = sy0 + 4 * PSH;                          // 576 B

    const int tid  = threadIdx.x;
    const int r    = tid >> 2;       // row 0..255
    const int p    = tid & 3;        // part: owns columns {64a + 16p + t}
    const int c    = blockIdx.x;
    const int offr = (r * (511 - r)) / 2 - r - 1;      // off(r) - r - 1

    // ===== stage packed W -> LDS as f16 (0.5*w), coalesced =====
    {
        const float4* Wc4 = (const float4*)(W + (size_t)c * NGF);
        #pragma unroll
        for (int k = 0; k < 7; ++k)                    // q <= 7167 < NQ: unguarded
            U2[tid + 1024 * k] = cvt2(Wc4[tid + 1024 * k]);
        int q = tid + 7168;
        if (q < NQ) U2[q] = cvt2(Wc4[q]);
    }
    const float xr = x[(size_t)r * CLS + c];
    if (p == 0) sy0[yaddr(r)] = (h16)xr;
    __syncthreads();                                   // U + y0 visible

    // ===== gather S[r][g] for owned columns -> sreg (f16x2), 3-path =====
    unsigned sreg[32];
    {
        #pragma unroll
        for (int a = 0; a < 4; ++a) {
            const int g0 = 64 * a + 16 * p;
            if (g0 > r) {
                // ---- pure upper: contiguous U[au0..au0+15], vectorized ----
                int au0 = offr + g0;
                unsigned d[9];
                #pragma unroll
                for (int i = 0; i < 9; ++i) d[i] = Ud[(au0 >> 1) + i];
                const bool odd = (au0 & 1);
                #pragma unroll
                for (int i = 0; i < 8; ++i) {
                    unsigned ev = d[i];
                    unsigned od = __builtin_amdgcn_alignbit(d[i + 1], d[i], 16);
                    sreg[8 * a + i] = odd ? od : ev;
                }
            } else if (g0 + 15 < r) {
                // ---- pure lower: strided scalar, negate, no clamps ----
                int g  = g0;
                int al = ((g0 * (511 - g0)) >> 1) + r - g0 - 1;
                unsigned wacc = 0;
                #pragma unroll
                for (int t = 0; t < 16; ++t) {
                    unsigned h = U[al] ^ 0x8000u;
                    if (t & 1) { wacc |= h << 16; sreg[8 * a + (t >> 1)] = wacc; }
                    else       { wacc  = h; }
                    al += 254 - g;
                    ++g;
                }
            } else {
                // ---- mixed (contains diagonal): general scalar path ----
                int g  = g0;
                int au = offr + g0;
                int al = ((g0 * (511 - g0)) >> 1) + r - g0 - 1;
                unsigned wacc = 0;
                #pragma unroll
                for (int t = 0; t < 16; ++t) {
                    int idx = (g < r) ? al : au;
                    idx = idx < 0 ? 0 : idx;           // only r==g==0 hits -1
                    unsigned h = U[idx];
                    h = (g < r) ? (h ^ 0x8000u) : h;
                    h = (g == r) ? 0u : h;
                    if (t & 1) { wacc |= h << 16; sreg[8 * a + (t >> 1)] = wacc; }
                    else       { wacc  = h; }
                    ++au;
                    al += 254 - g;
                    ++g;
                }
            }
        }
    }

    // ===== fixed-point iteration y <- x - S y ; out = x - 2 S y =====
    {
        h16* ycur = sy0;
        h16* ynxt = sy1;
        const int wr = yaddr(r);
        #pragma unroll
        for (int it = 0; it < NITER; ++it) {
            const uint4* yp = (const uint4*)(ycur + p * PSH);
            float a0 = 0.f, a1 = 0.f, a2 = 0.f, a3 = 0.f;
            #pragma unroll
            for (int k = 0; k < 8; ++k) {
                uint4 yv = yp[k];
                a0 = dot2f(sreg[4 * k + 0], yv.x, a0);
                a1 = dot2f(sreg[4 * k + 1], yv.y, a1);
                a2 = dot2f(sreg[4 * k + 2], yv.z, a2);
                a3 = dot2f(sreg[4 * k + 3], yv.w, a3);
            }
            float v = (a0 + a1) + (a2 + a3);           // partial (S y)_r
            v += __shfl_xor(v, 1);
            v += __shfl_xor(v, 2);                     // full (S y)_r on 4 lanes
            if (it < NITER - 1) {
                if (p == 0) ynxt[wr] = (h16)(xr - v);
                h16* t = ycur; ycur = ynxt; ynxt = t;
                bar_lds();
            } else {
                if (p == 0) out[(size_t)r * CLS + c] = xr - 2.f * v;
            }
        }
    }
}

extern "C" void kernel_launch(void* const* d_in, const int* in_sizes, int n_in,
                              void* d_out, int out_size, void* d_ws, size_t ws_size,
                              hipStream_t stream) {
    const float* x = (const float*)d_in[0];
    const float* W = (const float*)d_in[1];
    float* out = (float*)d_out;

    const size_t smem = 65536 + 2 * 4 * PSH * 2;       // 66688 B -> 2 blocks/CU
    hipFuncSetAttribute((const void*)cayley_kernel,
                        hipFuncAttributeMaxDynamicSharedMemorySize, (int)smem);
    hipLaunchKernelGGL(cayley_kernel, dim3(CLS), dim3(1024), smem, stream, x, W, out);
}